// Round 2
// baseline (76.045 us; speedup 1.0000x reference)
//
#include <hip/hip_runtime.h>

#define RCR 5.2f
#define RCA 3.5f
#define PI_F 3.14159265358979323846f

// TRIU[s1*4+s2] -> pair index (10 unordered species pairs)
__constant__ int c_triu[16] = {0,1,2,3, 1,4,5,6, 2,5,7,8, 3,6,8,9};

__global__ __launch_bounds__(64) void aev_kernel(
    const int* __restrict__ species,
    const float* __restrict__ coords,
    float* __restrict__ out,
    int NA)   // total atoms = N*64
{
    const int blk = blockIdx.x;
    const int n   = blk >> 6;   // molecule
    const int i   = blk & 63;   // center atom
    const int tid = threadIdx.x;

    __shared__ float sx[64], sy[64], sz[64];
    __shared__ int   ssp[64];
    __shared__ float dxs[64], dys[64], dzs[64], ds[64];
    __shared__ float pre_r[64];   // 0.25*fc_R(d) masked (0 if j==i or d>RCR)
    __shared__ float fca[64];     // fc_A(d) (only read for list members)
    __shared__ int   nbr[64];

    // ---- stage molecule ----
    const float* c = coords + (size_t)(n * 64) * 3;
    sx[tid]  = c[tid * 3 + 0];
    sy[tid]  = c[tid * 3 + 1];
    sz[tid]  = c[tid * 3 + 2];
    ssp[tid] = species[n * 64 + tid];
    __syncthreads();

    // ---- per-neighbor geometry (lane tid = candidate neighbor j) ----
    const float xi = sx[i], yi = sy[i], zi = sz[i];
    const float ddx = sx[tid] - xi;
    const float ddy = sy[tid] - yi;
    const float ddz = sz[tid] - zi;
    const float d   = sqrtf(ddx * ddx + ddy * ddy + ddz * ddz);
    dxs[tid] = ddx; dys[tid] = ddy; dzs[tid] = ddz; ds[tid] = d;

    const bool isj = (tid != i);
    pre_r[tid] = (isj && d <= RCR)
                   ? 0.25f * (0.5f * __cosf((PI_F / RCR) * d) + 0.5f) : 0.0f;
    fca[tid]   = 0.5f * __cosf((PI_F / RCA) * d) + 0.5f;

    // ballot-compact the angular neighbor list (no atomics)
    const bool apred = isj && (d <= RCA);
    const unsigned long long bal = __ballot(apred);
    if (apred) {
        const int pos = __popcll(bal & ((1ull << tid) - 1ull));
        nbr[pos] = tid;
    }
    const int M = __popcll(bal);
    __syncthreads();

    // ---- radial gather: lane = output bin (species s, shell r) ----
    const int   my_s   = tid >> 4;
    const float my_shf = 0.9f + 0.26875f * (float)(tid & 15);
    float racc = 0.0f;
    #pragma unroll 4
    for (int j = 0; j < 64; j++) {
        const float t = ds[j] - my_shf;                 // LDS broadcast
        const float e = pre_r[j] * __expf(-16.0f * t * t);
        racc += (ssp[j] == my_s) ? e : 0.0f;
    }

    // ---- angular gather: lane owns bins b = tid + 64u, u=0..4 ----
    float acc[5];
    int   my_p[5];
    float my_shfa[5], my_cphi[5], my_sphi[5];
    #pragma unroll
    for (int u = 0; u < 5; u++) {
        const int b = tid + 64 * u;          // angular bin in [0,320)
        my_p[u] = b >> 5;
        const int a = (b >> 3) & 3;
        const int z = b & 7;
        my_shfa[u] = 0.9f + 0.65f * (float)a;
        const float phi = (PI_F / 16.0f) * (float)(1 + 2 * z);
        float sp_, cp_;
        __sincosf(phi, &sp_, &cp_);
        my_cphi[u] = cp_;
        my_sphi[u] = sp_;
        acc[u] = 0.0f;
    }

    for (int jj = 1; jj < M; jj++) {
        const int j = nbr[jj];
        const float dij = ds[j];
        const float xj = dxs[j], yj = dys[j], zj = dzs[j];
        const float fcj = fca[j];
        const int sj4 = ssp[j] * 4;
        for (int kk = 0; kk < jj; kk++) {
            const int k = nbr[kk];
            const float dik = ds[k];
            const float dot = xj * dxs[k] + yj * dys[k] + zj * dzs[k];
            float cosv = 0.95f * dot * __frcp_rn(dij * dik);
            cosv = fminf(0.95f, fmaxf(-0.95f, cosv));
            const float sinv = sqrtf(1.0f - cosv * cosv);
            const float base2 = 2.0f * fcj * fca[k];
            const float davg  = 0.5f * (dij + dik);
            const int   pidx  = c_triu[sj4 + ssp[k]];
            #pragma unroll
            for (int u = 0; u < 5; u++) {
                const float t  = davg - my_shfa[u];
                const float e  = base2 * __expf(-8.0f * t * t);
                const float w  = cosv * my_cphi[u] + sinv * my_sphi[u];
                const float tz = 0.5f + 0.5f * w;
                const float t2 = tz * tz, t4 = t2 * t2, t8 = t4 * t4;
                const float t16 = t8 * t8, t32 = t16 * t16;
                acc[u] += (pidx == my_p[u]) ? e * t32 : 0.0f;
            }
        }
    }

    // ---- write out: species head, then this atom's 384 AEV values ----
    const int atom = n * 64 + i;
    if (tid == 0) out[atom] = (float)ssp[i];
    float* dstg = out + NA + (size_t)atom * 384;
    dstg[tid] = racc;
    #pragma unroll
    for (int u = 0; u < 5; u++) dstg[64 + tid + 64 * u] = acc[u];
}

extern "C" void kernel_launch(void* const* d_in, const int* in_sizes, int n_in,
                              void* d_out, int out_size, void* d_ws, size_t ws_size,
                              hipStream_t stream) {
    const int*   species = (const int*)d_in[0];
    const float* coords  = (const float*)d_in[1];
    float*       out     = (float*)d_out;
    const int NA = in_sizes[0];          // N * 64 atoms (1024)
    aev_kernel<<<NA, 64, 0, stream>>>(species, coords, out, NA);
}

// Round 3
// 67.810 us; speedup vs baseline: 1.1214x; 1.1214x over previous
//
#include <hip/hip_runtime.h>

#define RCR 5.2f
#define RCA 3.5f
#define PI_F 3.14159265358979323846f

__global__ __launch_bounds__(64) void aev_kernel(
    const int* __restrict__ species,
    const float* __restrict__ coords,
    float* __restrict__ out,
    int NA)   // total atoms = N*64
{
    const int blk = blockIdx.x;
    const int n   = blk >> 6;   // molecule
    const int i   = blk & 63;   // center atom
    const int tid = threadIdx.x;

    __shared__ float sx[64], sy[64], sz[64];
    __shared__ int   ssp[64];
    __shared__ float dxs[64], dys[64], dzs[64], ds[64];
    __shared__ float pre_r[64];   // 0.25*fc_R(d), masked
    __shared__ float fca[64];     // fc_A(d)
    __shared__ int   nbr[64];
    __shared__ float s_ang[320];

    // ---- stage molecule ----
    const float* c = coords + (size_t)(n * 64) * 3;
    sx[tid]  = c[tid * 3 + 0];
    sy[tid]  = c[tid * 3 + 1];
    sz[tid]  = c[tid * 3 + 2];
    ssp[tid] = species[n * 64 + tid];
    __syncthreads();

    // ---- per-lane geometry (lane = candidate neighbor j) ----
    const float xi = sx[i], yi = sy[i], zi = sz[i];
    const float ddx = sx[tid] - xi;
    const float ddy = sy[tid] - yi;
    const float ddz = sz[tid] - zi;
    const float d   = sqrtf(ddx * ddx + ddy * ddy + ddz * ddz);
    dxs[tid] = ddx; dys[tid] = ddy; dzs[tid] = ddz; ds[tid] = d;

    const bool isj = (tid != i);
    pre_r[tid] = (isj && d <= RCR)
                   ? 0.25f * (0.5f * __cosf((PI_F / RCR) * d) + 0.5f) : 0.0f;
    fca[tid]   = 0.5f * __cosf((PI_F / RCA) * d) + 0.5f;

    // ballot-compact angular neighbor list
    const bool apred = isj && (d <= RCA);
    const unsigned long long bal = __ballot(apred);
    if (apred) {
        const int pos = __popcll(bal & ((1ull << tid) - 1ull));
        nbr[pos] = tid;
    }
    const int M = __popcll(bal);

    // zero angular accumulator
    for (int f = tid; f < 320; f += 64) s_ang[f] = 0.0f;
    __syncthreads();

    // ---- radial gather: lane = output bin (species s, shell r); no atomics ----
    const int   my_s   = tid >> 4;
    const float my_shf = 0.9f + 0.26875f * (float)(tid & 15);
    float racc = 0.0f;
    #pragma unroll 8
    for (int j = 0; j < 64; j++) {
        const float t = ds[j] - my_shf;                 // LDS broadcast reads
        racc += (ssp[j] == my_s) ? pre_r[j] * __expf(-16.0f * t * t) : 0.0f;
    }

    // ---- angular: pairs distributed across lanes, fast math, LDS scatter ----
    const float CPHI[8] = { 0.98078528f,  0.83146961f,  0.55557023f,  0.19509032f,
                           -0.19509032f, -0.55557023f, -0.83146961f, -0.98078528f};
    const float SPHI[8] = { 0.19509032f,  0.55557023f,  0.83146961f,  0.98078528f,
                            0.98078528f,  0.83146961f,  0.55557023f,  0.19509032f};
    const float SHFA[4] = {0.9f, 1.55f, 2.2f, 2.85f};

    const int P = (M * (M - 1)) >> 1;   // unordered pairs jj>kk
    for (int q = tid; q < P; q += 64) {
        // triangular decode: q = jj*(jj-1)/2 + kk, kk < jj
        int jj = (int)((1.0f + sqrtf(1.0f + 8.0f * (float)q)) * 0.5f);
        while (((jj * (jj - 1)) >> 1) > q) --jj;
        while ((((jj + 1) * jj) >> 1) <= q) ++jj;
        const int kk = q - ((jj * (jj - 1)) >> 1);

        const int j = nbr[jj], k = nbr[kk];
        const float dij = ds[j], dik = ds[k];
        const float dot = dxs[j] * dxs[k] + dys[j] * dys[k] + dzs[j] * dzs[k];
        float cosv = 0.95f * dot * __builtin_amdgcn_rcpf(dij * dik);
        cosv = fminf(0.95f, fmaxf(-0.95f, cosv));
        const float sinv = sqrtf(fmaxf(0.0f, 1.0f - cosv * cosv));
        const float base2 = 2.0f * fca[j] * fca[k];
        const float davg  = 0.5f * (dij + dik);
        const int s1 = ssp[j], s2 = ssp[k];
        const int smin = (s1 < s2) ? s1 : s2;
        const int smax = (s1 < s2) ? s2 : s1;
        const int pidx = ((smin * (7 - smin)) >> 1) + smax;

        float f2[4];
        #pragma unroll
        for (int a = 0; a < 4; a++) {
            const float t = davg - SHFA[a];
            f2[a] = base2 * __expf(-8.0f * t * t);
        }
        float t32z[8];
        #pragma unroll
        for (int z = 0; z < 8; z++) {
            const float w  = 0.5f + 0.5f * (cosv * CPHI[z] + sinv * SPHI[z]);
            const float t2 = w * w, t4 = t2 * t2, t8 = t4 * t4, t16 = t8 * t8;
            t32z[z] = t16 * t16;
        }
        float* dst = &s_ang[pidx * 32];
        #pragma unroll
        for (int a = 0; a < 4; a++)
            #pragma unroll
            for (int z = 0; z < 8; z++)
                atomicAdd(&dst[a * 8 + z], f2[a] * t32z[z]);
    }
    __syncthreads();

    // ---- write out: species head, then this atom's 384 AEV values ----
    const int atom = n * 64 + i;
    if (tid == 0) out[atom] = (float)ssp[i];
    float* dstg = out + NA + (size_t)atom * 384;
    dstg[tid] = racc;
    #pragma unroll
    for (int u = 0; u < 5; u++) dstg[64 + tid + 64 * u] = s_ang[tid + 64 * u];
}

extern "C" void kernel_launch(void* const* d_in, const int* in_sizes, int n_in,
                              void* d_out, int out_size, void* d_ws, size_t ws_size,
                              hipStream_t stream) {
    const int*   species = (const int*)d_in[0];
    const float* coords  = (const float*)d_in[1];
    float*       out     = (float*)d_out;
    const int NA = in_sizes[0];          // N * 64 atoms (1024)
    aev_kernel<<<NA, 64, 0, stream>>>(species, coords, out, NA);
}

// Round 4
// 63.958 us; speedup vs baseline: 1.1890x; 1.0602x over previous
//
#include <hip/hip_runtime.h>

#define RCR 5.2f
#define RCA 3.5f
#define PI_F 3.14159265358979323846f

__global__ __launch_bounds__(64) void aev_kernel(
    const int* __restrict__ species,
    const float* __restrict__ coords,
    float* __restrict__ out,
    int NA)   // total atoms = N*64
{
    const int blk = blockIdx.x;
    const int n   = blk >> 6;   // molecule
    const int i   = blk & 63;   // center atom
    const int tid = threadIdx.x;

    __shared__ float sx[64], sy[64], sz[64];
    __shared__ int   ssp[64];
    __shared__ float dxs[64], dys[64], dzs[64], ds[64];
    __shared__ float pre_r[64];   // 0.25*fc_R(d), compacted by rnbr
    __shared__ float fca[64];     // fc_A(d)
    __shared__ int   nbr[64];     // angular list
    __shared__ int   rnbr[64];    // radial list
    __shared__ float s_ang[320];

    // ---- stage molecule ----
    const float* c = coords + (size_t)(n * 64) * 3;
    sx[tid]  = c[tid * 3 + 0];
    sy[tid]  = c[tid * 3 + 1];
    sz[tid]  = c[tid * 3 + 2];
    ssp[tid] = species[n * 64 + tid];
    __syncthreads();

    // ---- per-lane geometry (lane = candidate neighbor j) ----
    const float xi = sx[i], yi = sy[i], zi = sz[i];
    const float ddx = sx[tid] - xi;
    const float ddy = sy[tid] - yi;
    const float ddz = sz[tid] - zi;
    const float d   = sqrtf(ddx * ddx + ddy * ddy + ddz * ddz);
    dxs[tid] = ddx; dys[tid] = ddy; dzs[tid] = ddz; ds[tid] = d;

    const bool isj = (tid != i);
    pre_r[tid] = 0.25f * (0.5f * __cosf((PI_F / RCR) * d) + 0.5f);
    fca[tid]   = 0.5f * __cosf((PI_F / RCA) * d) + 0.5f;

    // ballot-compact radial neighbor list
    const bool rpred = isj && (d <= RCR);
    const unsigned long long rbal = __ballot(rpred);
    if (rpred) {
        const int pos = __popcll(rbal & ((1ull << tid) - 1ull));
        rnbr[pos] = tid;
    }
    const int MR = __popcll(rbal);

    // ballot-compact angular neighbor list
    const bool apred = isj && (d <= RCA);
    const unsigned long long bal = __ballot(apred);
    if (apred) {
        const int pos = __popcll(bal & ((1ull << tid) - 1ull));
        nbr[pos] = tid;
    }
    const int M = __popcll(bal);

    // zero angular accumulator
    for (int f = tid; f < 320; f += 64) s_ang[f] = 0.0f;
    __syncthreads();

    // ---- radial gather over compacted list: lane = bin (species, shell) ----
    const int   my_s   = tid >> 4;
    const float my_shf = 0.9f + 0.26875f * (float)(tid & 15);
    float racc = 0.0f;
    #pragma unroll 4
    for (int jj = 0; jj < MR; jj++) {
        const int j = rnbr[jj];                         // wave-uniform broadcast
        const float t = ds[j] - my_shf;
        racc += (ssp[j] == my_s) ? pre_r[j] * __expf(-16.0f * t * t) : 0.0f;
    }

    // ---- angular: pairs distributed across lanes, fast math, LDS scatter ----
    const float CPHI[8] = { 0.98078528f,  0.83146961f,  0.55557023f,  0.19509032f,
                           -0.19509032f, -0.55557023f, -0.83146961f, -0.98078528f};
    const float SPHI[8] = { 0.19509032f,  0.55557023f,  0.83146961f,  0.98078528f,
                            0.98078528f,  0.83146961f,  0.55557023f,  0.19509032f};
    const float SHFA[4] = {0.9f, 1.55f, 2.2f, 2.85f};

    const int P = (M * (M - 1)) >> 1;   // unordered pairs jj>kk
    for (int q = tid; q < P; q += 64) {
        // triangular decode: q = jj*(jj-1)/2 + kk, kk < jj
        int jj = (int)((1.0f + sqrtf(1.0f + 8.0f * (float)q)) * 0.5f);
        while (((jj * (jj - 1)) >> 1) > q) --jj;
        while ((((jj + 1) * jj) >> 1) <= q) ++jj;
        const int kk = q - ((jj * (jj - 1)) >> 1);

        const int j = nbr[jj], k = nbr[kk];
        const float dij = ds[j], dik = ds[k];
        const float dot = dxs[j] * dxs[k] + dys[j] * dys[k] + dzs[j] * dzs[k];
        float cosv = 0.95f * dot * __builtin_amdgcn_rcpf(dij * dik);
        cosv = fminf(0.95f, fmaxf(-0.95f, cosv));
        const float sinv = sqrtf(fmaxf(0.0f, 1.0f - cosv * cosv));
        const float base2 = 2.0f * fca[j] * fca[k];
        const float davg  = 0.5f * (dij + dik);
        const int s1 = ssp[j], s2 = ssp[k];
        const int smin = (s1 < s2) ? s1 : s2;
        const int smax = (s1 < s2) ? s2 : s1;
        const int pidx = ((smin * (7 - smin)) >> 1) + smax;

        float f2[4];
        #pragma unroll
        for (int a = 0; a < 4; a++) {
            const float t = davg - SHFA[a];
            f2[a] = base2 * __expf(-8.0f * t * t);
        }
        float t32z[8];
        #pragma unroll
        for (int z = 0; z < 8; z++) {
            const float w  = 0.5f + 0.5f * (cosv * CPHI[z] + sinv * SPHI[z]);
            const float t2 = w * w, t4 = t2 * t2, t8 = t4 * t4, t16 = t8 * t8;
            t32z[z] = t16 * t16;
        }
        float* dst = &s_ang[pidx * 32];
        #pragma unroll
        for (int a = 0; a < 4; a++)
            #pragma unroll
            for (int z = 0; z < 8; z++)
                atomicAdd(&dst[a * 8 + z], f2[a] * t32z[z]);
    }
    __syncthreads();

    // ---- write out: species head, then this atom's 384 AEV values ----
    const int atom = n * 64 + i;
    if (tid == 0) out[atom] = (float)ssp[i];
    float* dstg = out + NA + (size_t)atom * 384;
    dstg[tid] = racc;
    #pragma unroll
    for (int u = 0; u < 5; u++) dstg[64 + tid + 64 * u] = s_ang[tid + 64 * u];
}

extern "C" void kernel_launch(void* const* d_in, const int* in_sizes, int n_in,
                              void* d_out, int out_size, void* d_ws, size_t ws_size,
                              hipStream_t stream) {
    const int*   species = (const int*)d_in[0];
    const float* coords  = (const float*)d_in[1];
    float*       out     = (float*)d_out;
    const int NA = in_sizes[0];          // N * 64 atoms (1024)
    aev_kernel<<<NA, 64, 0, stream>>>(species, coords, out, NA);
}